// Round 15
// baseline (741.655 us; speedup 1.0000x reference)
//
#include <hip/hip_runtime.h>
#include <math.h>

typedef __bf16 bf16_t;
typedef __bf16 bf16x4 __attribute__((ext_vector_type(4)));
typedef __bf16 bf16x8 __attribute__((ext_vector_type(8)));
typedef float f32x4 __attribute__((ext_vector_type(4)));

#define GLDS(gp, lp) __builtin_amdgcn_global_load_lds( \
    (const __attribute__((address_space(1))) void*)(gp), \
    (__attribute__((address_space(3))) void*)(lp), 16, 0, 0)

static constexpr int B_    = 2;
static constexpr int T_    = 16;
static constexpr int HW_   = 576;
static constexpr int NH_   = 16;
static constexpr int TOK_  = B_ * T_ * HW_;   // 18432
static constexpr int D_    = 1024;
static constexpr int D3_   = 3072;

// ---------------------------------------------------------------------------
// prep: fused fp32->bf16 convert of x + 4 weight transpose+converts.
// ---------------------------------------------------------------------------
__global__ __launch_bounds__(256) void prep(const float* __restrict__ x,
                                            bf16_t* __restrict__ x_bf,
                                            const float* __restrict__ wqs,
                                            bf16_t* __restrict__ wTqs,
                                            const float* __restrict__ wps,
                                            bf16_t* __restrict__ wTps,
                                            const float* __restrict__ wqt,
                                            bf16_t* __restrict__ wTqt,
                                            const float* __restrict__ wpt,
                                            bf16_t* __restrict__ wTpt)
{
    const int bid = blockIdx.x, tid = threadIdx.x;
    if (bid < 4096) {
        const long n = (long)TOK_ * D_;
        for (long i = ((long)bid * 256 + tid) * 4; i < n; i += 4096L * 1024) {
            float4 v = *(const float4*)(x + i);
            bf16x4 o;
            o[0] = (bf16_t)v.x; o[1] = (bf16_t)v.y;
            o[2] = (bf16_t)v.z; o[3] = (bf16_t)v.w;
            *(bf16x4*)(x_bf + i) = o;
        }
        return;
    }
    const float* in; bf16_t* out; int C, b2;
    if (bid < 7168)       { in = wqs; out = wTqs; C = 3072; b2 = bid - 4096; }
    else if (bid < 8192)  { in = wps; out = wTps; C = 1024; b2 = bid - 7168; }
    else if (bid < 11264) { in = wqt; out = wTqt; C = 3072; b2 = bid - 8192; }
    else                  { in = wpt; out = wTpt; C = 1024; b2 = bid - 11264; }
    const int nbx = C >> 5;
    const int cb = (b2 % nbx) * 32, rb = (b2 / nbx) * 32;
    const int tx = tid & 31, ty = tid >> 5;   // 32 x 8
    __shared__ bf16_t tile[32][33];
    #pragma unroll
    for (int i = 0; i < 32; i += 8)
        tile[ty + i][tx] = (bf16_t)in[(long)(rb + ty + i) * C + cb + tx];
    __syncthreads();
    #pragma unroll
    for (int i = 0; i < 32; i += 8)
        out[(long)(cb + ty + i) * 1024 + rb + tx] = tile[tx][ty + i];
}

// ---------------------------------------------------------------------------
// In-place V transpose (temporal): block bhw reads the V-third of its own
// 16 qkv rows into LDS, then writes back transposed as [h][d][t] into the
// same rows' V-holes: qkv[(bhw*16+h)*3072 + 2048 + d*16 + t].
// Block-local in-place => race-free; writes are 32B-contiguous per thread.
// ---------------------------------------------------------------------------
__global__ __launch_bounds__(256) void vtrans_t_ip(bf16_t* __restrict__ qkv_t)
{
    __shared__ bf16_t tile[16][1026];
    const int tid = threadIdx.x;
    const long bhw = blockIdx.x;              // 0..1151
    #pragma unroll
    for (int it = 0; it < 8; it++) {
        const int c = it * 256 + tid;         // 0..2047 vec8 chunks
        const int row = c >> 7, col = (c & 127) * 8;
        *(bf16x8*)&tile[row][col] =
            *(const bf16x8*)(qkv_t + (bhw * 16 + row) * D3_ + 2048 + col);
    }
    __syncthreads();
    #pragma unroll
    for (int it = 0; it < 4; it++) {
        const int hd = it * 256 + tid;        // h*64+d, 0..1023
        bf16x8 v0, v1;
        #pragma unroll
        for (int t = 0; t < 8; t++) v0[t] = tile[t][hd];
        #pragma unroll
        for (int t = 0; t < 8; t++) v1[t] = tile[8 + t][hd];
        bf16_t* dst = qkv_t + (bhw * 16 + (hd >> 6)) * D3_ + 2048 + (long)(hd & 63) * 16;
        *(bf16x8*)dst = v0;
        *(bf16x8*)(dst + 8) = v1;
    }
}

// ---------------------------------------------------------------------------
// GEMM 128x128, 2-phase dbuf: C = A * BT^T + bias (+ resf f32 / resb bf16).
// 1-D grid with bijective XCD swizzle (T1): consecutive swizzled tiles
// (sharing an A-panel) land on one XCD's L2. ntx = column tiles.
// vmode=1 (spatial QKV): V-cols (>=2048) -> vout=vt[(bt*16+h)][d][hw].
// tperm permutes store rows (b,t,hw)->(b,hw,t).
// ---------------------------------------------------------------------------
__global__ __launch_bounds__(256) void gemm_bt(const bf16_t* __restrict__ A,
                                               const bf16_t* __restrict__ BT,
                                               const float* __restrict__ bias,
                                               const float* __restrict__ resf,
                                               const bf16_t* __restrict__ resb,
                                               bf16_t* __restrict__ Cb,
                                               float* __restrict__ Cf,
                                               bf16_t* __restrict__ vout,
                                               int vmode, int ntx,
                                               int M, int N, int K, int tperm)
{
    __shared__ bf16_t As[2][128 * 32];
    __shared__ bf16_t Bs[2][128 * 32];
    const int tid  = threadIdx.x;
    const int lane = tid & 63, wid = tid >> 6;
    const int wr   = wid >> 1, wc = wid & 1;
    const int l15  = lane & 15, lhi = lane >> 4;
    // bijective XCD swizzle (gridDim.x % 8 == 0)
    const int cpx = gridDim.x >> 3;
    const int swz = (blockIdx.x & 7) * cpx + (blockIdx.x >> 3);
    const long row0 = (long)(swz / ntx) * 128;
    const long col0 = (long)(swz % ntx) * 128;
    const int  sr   = tid >> 2;        // 0..63
    const int  sc   = (tid & 3) * 8;   // 0,8,16,24
    const bf16_t* Ag = A  + (row0 + sr) * (long)K + sc;
    const bf16_t* Bg = BT + (col0 + sr) * (long)K + sc;

    f32x4 acc[4][4] = {};

    GLDS(Ag,                &As[0][tid * 8]);
    GLDS(Ag + 64 * (long)K, &As[0][2048 + tid * 8]);
    GLDS(Bg,                &Bs[0][tid * 8]);
    GLDS(Bg + 64 * (long)K, &Bs[0][2048 + tid * 8]);
    __syncthreads();

    const int nt = K >> 5;
    int cur = 0;
    for (int t = 0; t < nt; ++t) {
        if (t + 1 < nt) {
            const int k0 = (t + 1) << 5;
            GLDS(Ag + k0,                &As[cur ^ 1][tid * 8]);
            GLDS(Ag + 64 * (long)K + k0, &As[cur ^ 1][2048 + tid * 8]);
            GLDS(Bg + k0,                &Bs[cur ^ 1][tid * 8]);
            GLDS(Bg + 64 * (long)K + k0, &Bs[cur ^ 1][2048 + tid * 8]);
        }

        bf16x8 a[4], b[4];
        #pragma unroll
        for (int i = 0; i < 4; i++)
            a[i] = *(const bf16x8*)&As[cur][(wr * 64 + i * 16 + l15) * 32 + lhi * 8];
        #pragma unroll
        for (int j = 0; j < 4; j++)
            b[j] = *(const bf16x8*)&Bs[cur][(wc * 64 + j * 16 + l15) * 32 + lhi * 8];

        __builtin_amdgcn_s_setprio(1);
        #pragma unroll
        for (int i = 0; i < 4; i++)
            #pragma unroll
            for (int j = 0; j < 4; j++)
                acc[i][j] = __builtin_amdgcn_mfma_f32_16x16x32_bf16(a[i], b[j], acc[i][j], 0, 0, 0);
        __builtin_amdgcn_s_setprio(0);

        __syncthreads();
        cur ^= 1;
    }

    // epilogue: C/D frag mapping col=lane&15, row=(lane>>4)*4+reg
    #pragma unroll
    for (int i = 0; i < 4; i++) {
        #pragma unroll
        for (int j = 0; j < 4; j++) {
            const long col  = col0 + wc * 64 + j * 16 + l15;
            const long rowb = row0 + wr * 64 + i * 16 + lhi * 4;
            float v4[4];
            #pragma unroll
            for (int r = 0; r < 4; r++) {
                float v = acc[i][j][r] + bias[col];
                if (resf) v += resf[(rowb + r) * (long)N + col];
                if (resb) v += (float)resb[(rowb + r) * (long)N + col];
                v4[r] = v;
            }
            if (vmode == 1 && col >= 2048) {
                // vt[(bt*16+hh)][d][hw]; 4 rows = 4 consecutive hw
                const int hh = ((int)col - 2048) >> 6, d = ((int)col - 2048) & 63;
                const int r0i = (int)rowb;
                const int bt0 = r0i / HW_, hw0 = r0i - bt0 * HW_;
                bf16x4 pk;
                #pragma unroll
                for (int r = 0; r < 4; r++) pk[r] = (bf16_t)v4[r];
                *(bf16x4*)(vout + ((long)(bt0 * 16 + hh) * 64 + d) * HW_ + hw0) = pk;
            } else {
                #pragma unroll
                for (int r = 0; r < 4; r++) {
                    const long row = rowb + r;
                    long srow = row;
                    if (tperm) {
                        const int ri  = (int)row;
                        const int bb  = ri / (T_ * HW_);
                        const int rem = ri - bb * (T_ * HW_);
                        const int tt  = rem / HW_;
                        const int hh2 = rem - tt * HW_;
                        srow = ((long)bb * HW_ + hh2) * T_ + tt;
                    }
                    if (Cf) Cf[srow * (long)N + col] = v4[r];
                    if (Cb) Cb[srow * (long)N + col] = (bf16_t)v4[r];
                }
            }
        }
    }
}

// ---------------------------------------------------------------------------
// Spatial attention, MFMA flash-style (unchanged from R9/R11).
// ---------------------------------------------------------------------------
__global__ __launch_bounds__(256) void attn_spatial(const bf16_t* __restrict__ qkv,
                                                    const bf16_t* __restrict__ vt,
                                                    bf16_t* __restrict__ out)
{
    __shared__ bf16_t Ks[2][64 * 64];
    __shared__ bf16_t Vts[2][64 * 64];
    __shared__ bf16_t Pws[4][2][16 * 72];
    const int tid = threadIdx.x, lane = tid & 63, w = tid >> 6;
    const int qt = blockIdx.x;            // 0..4 (qt==4: 64-row tail)
    const int g  = blockIdx.y;            // 0..511
    const int h  = g & 15, bt = g >> 4;
    const long base = (long)bt * HW_;
    const int l15 = lane & 15, lhi = lane >> 4;
    const int row0 = qt * 128 + w * 16;
    const int nR = (qt == 4) ? 1 : 2;

    bf16x8 q[2][2];
    #pragma unroll
    for (int rg = 0; rg < 2; rg++) if (rg < nR) {
        #pragma unroll
        for (int kk = 0; kk < 2; kk++) {
            bf16x8 tq = *(const bf16x8*)(qkv + (base + row0 + rg * 64 + l15) * D3_
                                         + h * 64 + kk * 32 + lhi * 8);
            #pragma unroll
            for (int e = 0; e < 8; e++) tq[e] = (bf16_t)((float)tq[e] * 0.125f);
            q[rg][kk] = tq;
        }
    }

    const bf16_t* Kg = qkv + base * D3_ + 1024 + h * 64;
    const bf16_t* Vg = vt + (long)g * (64 * 576);

#define STAGEKV(kt, bq) do {                                                  \
        _Pragma("unroll")                                                     \
        for (int i_ = 0; i_ < 2; i_++) {                                      \
            const int c_ = i_ * 256 + tid;                                    \
            const int r_ = c_ >> 3, cb_ = (c_ & 7) << 4;                      \
            const int cs_ = cb_ ^ ((r_ & 7) << 4);                            \
            GLDS(Kg + (long)((kt) * 64 + r_) * D3_ + (cs_ >> 1),              \
                 (char*)Ks[bq] + c_ * 16);                                    \
            GLDS(Vg + (long)r_ * 576 + (kt) * 64 + (cs_ >> 1),               \
                 (char*)Vts[bq] + c_ * 16);                                   \
        }                                                                     \
    } while (0)

    float lp[2][4] = {};
    f32x4 o[2][4] = {};

    STAGEKV(0, 0);

    for (int kt = 0; kt < 9; kt++) {
        const int cur = kt & 1;
        __syncthreads();
        if (kt < 8) STAGEKV(kt + 1, cur ^ 1);

        f32x4 acc[2][4] = {};
        #pragma unroll
        for (int j = 0; j < 4; j++) {
            const int key = j * 16 + l15;
            #pragma unroll
            for (int kk = 0; kk < 2; kk++) {
                const int boff = key * 128 + ((kk * 64 + lhi * 16) ^ ((key & 7) << 4));
                bf16x8 kb = *(const bf16x8*)((const char*)Ks[cur] + boff);
                acc[0][j] = __builtin_amdgcn_mfma_f32_16x16x32_bf16(q[0][kk], kb, acc[0][j], 0, 0, 0);
                if (nR > 1)
                    acc[1][j] = __builtin_amdgcn_mfma_f32_16x16x32_bf16(q[1][kk], kb, acc[1][j], 0, 0, 0);
            }
        }

        #pragma unroll
        for (int rg = 0; rg < 2; rg++) if (rg < nR) {
            #pragma unroll
            for (int r = 0; r < 4; r++) {
                const float p0 = __expf(acc[rg][0][r]);
                const float p1 = __expf(acc[rg][1][r]);
                const float p2 = __expf(acc[rg][2][r]);
                const float p3 = __expf(acc[rg][3][r]);
                lp[rg][r] += (p0 + p1) + (p2 + p3);
                const int prow = (lhi * 4 + r) * 72 + l15;
                Pws[w][rg][prow]      = (bf16_t)p0;
                Pws[w][rg][prow + 16] = (bf16_t)p1;
                Pws[w][rg][prow + 32] = (bf16_t)p2;
                Pws[w][rg][prow + 48] = (bf16_t)p3;
            }
        }
        __builtin_amdgcn_sched_barrier(0);

        bf16x8 pa[2][2];
        #pragma unroll
        for (int kk = 0; kk < 2; kk++) {
            pa[0][kk] = *(const bf16x8*)&Pws[w][0][l15 * 72 + kk * 32 + lhi * 8];
            if (nR > 1)
                pa[1][kk] = *(const bf16x8*)&Pws[w][1][l15 * 72 + kk * 32 + lhi * 8];
        }
        #pragma unroll
        for (int j = 0; j < 4; j++) {
            const int vrow = j * 16 + l15;
            #pragma unroll
            for (int kk = 0; kk < 2; kk++) {
                const int boff = vrow * 128 + ((kk * 64 + lhi * 16) ^ ((vrow & 7) << 4));
                bf16x8 vb = *(const bf16x8*)((const char*)Vts[cur] + boff);
                o[0][j] = __builtin_amdgcn_mfma_f32_16x16x32_bf16(pa[0][kk], vb, o[0][j], 0, 0, 0);
                if (nR > 1)
                    o[1][j] = __builtin_amdgcn_mfma_f32_16x16x32_bf16(pa[1][kk], vb, o[1][j], 0, 0, 0);
            }
        }
        __builtin_amdgcn_sched_barrier(0);
    }
#undef STAGEKV

    #pragma unroll
    for (int rg = 0; rg < 2; rg++) if (rg < nR) {
        #pragma unroll
        for (int r = 0; r < 4; r++) {
            float l = lp[rg][r];
            #pragma unroll
            for (int off = 1; off < 16; off <<= 1) l += __shfl_xor(l, off);
            const float inv = 1.f / l;
            const long row = base + row0 + rg * 64 + lhi * 4 + r;
            #pragma unroll
            for (int j = 0; j < 4; j++)
                out[row * (long)D_ + h * 64 + j * 16 + l15] = (bf16_t)(o[rg][j][r] * inv);
        }
    }
}

// ---------------------------------------------------------------------------
// Temporal attention, MFMA; no-max softmax. V read from the (in-place
// transposed) V-holes of qkv rows: qkv[g'*3072 + 2048 + d*16 + t].
// ---------------------------------------------------------------------------
__global__ __launch_bounds__(256) void attn_temporal(const bf16_t* __restrict__ qkv_t,
                                                     bf16_t* __restrict__ out)
{
    __shared__ bf16_t Plds[4][16 * 24];
    const int tid = threadIdx.x, lane = tid & 63, w = tid >> 6;
    const int l15 = lane & 15, lhi = lane >> 4;
    const int bhw = blockIdx.x;            // 0..1151
    const int b = bhw / HW_, hw = bhw % HW_;
    const long base_row = (long)bhw * T_;
    const bf16_t* qrow = qkv_t + (base_row + l15) * D3_;

    #pragma unroll
    for (int i = 0; i < 4; i++) {
        const int h = w * 4 + i;
        bf16x8 q0 = *(const bf16x8*)(qrow + h * 64 + lhi * 8);
        bf16x8 q1 = *(const bf16x8*)(qrow + h * 64 + 32 + lhi * 8);
        bf16x8 k0 = *(const bf16x8*)(qrow + 1024 + h * 64 + lhi * 8);
        bf16x8 k1 = *(const bf16x8*)(qrow + 1024 + h * 64 + 32 + lhi * 8);
        f32x4 acc = {};
        acc = __builtin_amdgcn_mfma_f32_16x16x32_bf16(q0, k0, acc, 0, 0, 0);
        acc = __builtin_amdgcn_mfma_f32_16x16x32_bf16(q1, k1, acc, 0, 0, 0);

        #pragma unroll
        for (int r = 0; r < 4; r++) {
            const int tq = lhi * 4 + r;
            float p = (l15 <= tq) ? __expf(acc[r] * 0.125f) : 0.f;
            float sum = p;
            #pragma unroll
            for (int off = 1; off < 16; off <<= 1) sum += __shfl_xor(sum, off);
            Plds[w][tq * 24 + l15] = (bf16_t)(p / sum);
        }
        __builtin_amdgcn_sched_barrier(0);

        bf16x8 pa = {};
        if (lhi < 2) pa = *(const bf16x8*)&Plds[w][l15 * 24 + lhi * 8];

        const bf16_t* vg = qkv_t + ((long)bhw * 16 + h) * D3_ + 2048;
        #pragma unroll
        for (int j = 0; j < 4; j++) {
            bf16x8 vb = {};
            if (lhi < 2) vb = *(const bf16x8*)(vg + (long)(j * 16 + l15) * 16 + lhi * 8);
            f32x4 o = {};
            o = __builtin_amdgcn_mfma_f32_16x16x32_bf16(pa, vb, o, 0, 0, 0);
            #pragma unroll
            for (int r = 0; r < 4; r++) {
                const int tq = lhi * 4 + r;
                out[(((long)b * T_ + tq) * HW_ + hw) * D_ + h * 64 + j * 16 + l15] = (bf16_t)o[r];
            }
        }
        __builtin_amdgcn_sched_barrier(0);
    }
}

// ---------------------------------------------------------------------------
extern "C" void kernel_launch(void* const* d_in, const int* in_sizes, int n_in,
                              void* d_out, int out_size, void* d_ws, size_t ws_size,
                              hipStream_t stream)
{
    const float* x       = (const float*)d_in[0];
    const float* ws_qkv  = (const float*)d_in[1];
    const float* bs_qkv  = (const float*)d_in[2];
    const float* ws_proj = (const float*)d_in[3];
    const float* bs_proj = (const float*)d_in[4];
    const float* wt_qkv  = (const float*)d_in[5];
    const float* bt_qkv  = (const float*)d_in[6];
    const float* wt_proj = (const float*)d_in[7];
    const float* bt_proj = (const float*)d_in[8];
    float* out = (float*)d_out;
    (void)in_sizes; (void)n_in; (void)out_size;

    // workspace layout (bytes)
    char* ws = (char*)d_ws;
    bf16_t* qkv   = (bf16_t*)(ws);                  // 18432*3072*2 = 113,246,208
    bf16_t* x_bf  = (bf16_t*)(ws + 113246208L);     // 18432*1024*2 =  37,748,736
    bf16_t* att   = x_bf;                           // alias: att written after x_bf dead
    bf16_t* x1_bf = (bf16_t*)(ws + 150994944L);     //                 37,748,736
    bf16_t* vt    = x1_bf;                          // alias: vt dead before x1_bf written
    bf16_t* wTqs  = (bf16_t*)(ws + 188743680L);     // 3072*1024*2 =    6,291,456
    bf16_t* wTps  = (bf16_t*)(ws + 195035136L);     // 1024*1024*2 =    2,097,152
    bf16_t* wTqt  = (bf16_t*)(ws + 197132288L);     //                  6,291,456
    bf16_t* wTpt  = (bf16_t*)(ws + 203423744L);     //                  2,097,152
    if (ws_size < 205520896UL) return;              // visible failure: out stays 0

    prep<<<12288, 256, 0, stream>>>(x, x_bf, ws_qkv, wTqs, ws_proj, wTps,
                                    wt_qkv, wTqt, wt_proj, wTpt);

    // ---- spatial branch ----  (V fused into vt; x1 bf16-only)
    gemm_bt<<<24 * 144, 256, 0, stream>>>(x_bf, wTqs, bs_qkv,
                                          nullptr, nullptr,
                                          qkv, nullptr, vt, 1, 24,
                                          TOK_, D3_, D_, 0);
    attn_spatial<<<dim3(5, 512), 256, 0, stream>>>(qkv, vt, att);
    gemm_bt<<<8 * 144, 256, 0, stream>>>(att, wTps, bs_proj,
                                         x, nullptr,
                                         x1_bf, nullptr, nullptr, 0, 8,
                                         TOK_, D_, D_, 0);
    // ---- temporal branch ----  (qkv rows (b,hw,t), coalesced V write;
    //      then block-local in-place transpose of the V-third)
    gemm_bt<<<24 * 144, 256, 0, stream>>>(x1_bf, wTqt, bt_qkv,
                                          nullptr, nullptr,
                                          qkv, nullptr, nullptr, 0, 24,
                                          TOK_, D3_, D_, 1);
    vtrans_t_ip<<<1152, 256, 0, stream>>>(qkv);
    attn_temporal<<<1152, 256, 0, stream>>>(qkv, att);
    gemm_bt<<<8 * 144, 256, 0, stream>>>(att, wTpt, bt_proj,
                                         nullptr, x1_bf,
                                         nullptr, out, nullptr, 0, 8,
                                         TOK_, D_, D_, 0);
}

// Round 16
// 715.991 us; speedup vs baseline: 1.0358x; 1.0358x over previous
//
#include <hip/hip_runtime.h>
#include <math.h>

typedef __bf16 bf16_t;
typedef __bf16 bf16x4 __attribute__((ext_vector_type(4)));
typedef __bf16 bf16x8 __attribute__((ext_vector_type(8)));
typedef float f32x4 __attribute__((ext_vector_type(4)));

#define GLDS(gp, lp) __builtin_amdgcn_global_load_lds( \
    (const __attribute__((address_space(1))) void*)(gp), \
    (__attribute__((address_space(3))) void*)(lp), 16, 0, 0)

static constexpr int B_    = 2;
static constexpr int T_    = 16;
static constexpr int HW_   = 576;
static constexpr int NH_   = 16;
static constexpr int TOK_  = B_ * T_ * HW_;   // 18432
static constexpr int D_    = 1024;
static constexpr int D3_   = 3072;

// ---------------------------------------------------------------------------
// prep: fused fp32->bf16 convert of x + 4 weight transpose+converts.
// ---------------------------------------------------------------------------
__global__ __launch_bounds__(256) void prep(const float* __restrict__ x,
                                            bf16_t* __restrict__ x_bf,
                                            const float* __restrict__ wqs,
                                            bf16_t* __restrict__ wTqs,
                                            const float* __restrict__ wps,
                                            bf16_t* __restrict__ wTps,
                                            const float* __restrict__ wqt,
                                            bf16_t* __restrict__ wTqt,
                                            const float* __restrict__ wpt,
                                            bf16_t* __restrict__ wTpt)
{
    const int bid = blockIdx.x, tid = threadIdx.x;
    if (bid < 4096) {
        const long n = (long)TOK_ * D_;
        for (long i = ((long)bid * 256 + tid) * 4; i < n; i += 4096L * 1024) {
            float4 v = *(const float4*)(x + i);
            bf16x4 o;
            o[0] = (bf16_t)v.x; o[1] = (bf16_t)v.y;
            o[2] = (bf16_t)v.z; o[3] = (bf16_t)v.w;
            *(bf16x4*)(x_bf + i) = o;
        }
        return;
    }
    const float* in; bf16_t* out; int C, b2;
    if (bid < 7168)       { in = wqs; out = wTqs; C = 3072; b2 = bid - 4096; }
    else if (bid < 8192)  { in = wps; out = wTps; C = 1024; b2 = bid - 7168; }
    else if (bid < 11264) { in = wqt; out = wTqt; C = 3072; b2 = bid - 8192; }
    else                  { in = wpt; out = wTpt; C = 1024; b2 = bid - 11264; }
    const int nbx = C >> 5;
    const int cb = (b2 % nbx) * 32, rb = (b2 / nbx) * 32;
    const int tx = tid & 31, ty = tid >> 5;   // 32 x 8
    __shared__ bf16_t tile[32][33];
    #pragma unroll
    for (int i = 0; i < 32; i += 8)
        tile[ty + i][tx] = (bf16_t)in[(long)(rb + ty + i) * C + cb + tx];
    __syncthreads();
    #pragma unroll
    for (int i = 0; i < 32; i += 8)
        out[(long)(cb + ty + i) * 1024 + rb + tx] = tile[tx][ty + i];
}

// ---------------------------------------------------------------------------
// GEMM 128x128, 2-phase dbuf: C = A * BT^T + bias (+ resf f32 / resb bf16).
// 1-D grid with bijective XCD swizzle (T1). ntx = column tiles.
// vmode=1 (spatial QKV): V-cols (>=2048) -> vout=vt[(bt*16+h)][d][hw].
// tperm permutes store rows (b,t,hw)->(b,hw,t).
// ---------------------------------------------------------------------------
__global__ __launch_bounds__(256) void gemm_bt(const bf16_t* __restrict__ A,
                                               const bf16_t* __restrict__ BT,
                                               const float* __restrict__ bias,
                                               const float* __restrict__ resf,
                                               const bf16_t* __restrict__ resb,
                                               bf16_t* __restrict__ Cb,
                                               float* __restrict__ Cf,
                                               bf16_t* __restrict__ vout,
                                               int vmode, int ntx,
                                               int M, int N, int K, int tperm)
{
    __shared__ bf16_t As[2][128 * 32];
    __shared__ bf16_t Bs[2][128 * 32];
    const int tid  = threadIdx.x;
    const int lane = tid & 63, wid = tid >> 6;
    const int wr   = wid >> 1, wc = wid & 1;
    const int l15  = lane & 15, lhi = lane >> 4;
    // bijective XCD swizzle (gridDim.x % 8 == 0)
    const int cpx = gridDim.x >> 3;
    const int swz = (blockIdx.x & 7) * cpx + (blockIdx.x >> 3);
    const long row0 = (long)(swz / ntx) * 128;
    const long col0 = (long)(swz % ntx) * 128;
    const int  sr   = tid >> 2;        // 0..63
    const int  sc   = (tid & 3) * 8;   // 0,8,16,24
    const bf16_t* Ag = A  + (row0 + sr) * (long)K + sc;
    const bf16_t* Bg = BT + (col0 + sr) * (long)K + sc;

    f32x4 acc[4][4] = {};

    GLDS(Ag,                &As[0][tid * 8]);
    GLDS(Ag + 64 * (long)K, &As[0][2048 + tid * 8]);
    GLDS(Bg,                &Bs[0][tid * 8]);
    GLDS(Bg + 64 * (long)K, &Bs[0][2048 + tid * 8]);
    __syncthreads();

    const int nt = K >> 5;
    int cur = 0;
    for (int t = 0; t < nt; ++t) {
        if (t + 1 < nt) {
            const int k0 = (t + 1) << 5;
            GLDS(Ag + k0,                &As[cur ^ 1][tid * 8]);
            GLDS(Ag + 64 * (long)K + k0, &As[cur ^ 1][2048 + tid * 8]);
            GLDS(Bg + k0,                &Bs[cur ^ 1][tid * 8]);
            GLDS(Bg + 64 * (long)K + k0, &Bs[cur ^ 1][2048 + tid * 8]);
        }

        bf16x8 a[4], b[4];
        #pragma unroll
        for (int i = 0; i < 4; i++)
            a[i] = *(const bf16x8*)&As[cur][(wr * 64 + i * 16 + l15) * 32 + lhi * 8];
        #pragma unroll
        for (int j = 0; j < 4; j++)
            b[j] = *(const bf16x8*)&Bs[cur][(wc * 64 + j * 16 + l15) * 32 + lhi * 8];

        __builtin_amdgcn_s_setprio(1);
        #pragma unroll
        for (int i = 0; i < 4; i++)
            #pragma unroll
            for (int j = 0; j < 4; j++)
                acc[i][j] = __builtin_amdgcn_mfma_f32_16x16x32_bf16(a[i], b[j], acc[i][j], 0, 0, 0);
        __builtin_amdgcn_s_setprio(0);

        __syncthreads();
        cur ^= 1;
    }

    // epilogue: C/D frag mapping col=lane&15, row=(lane>>4)*4+reg
    #pragma unroll
    for (int i = 0; i < 4; i++) {
        #pragma unroll
        for (int j = 0; j < 4; j++) {
            const long col  = col0 + wc * 64 + j * 16 + l15;
            const long rowb = row0 + wr * 64 + i * 16 + lhi * 4;
            float v4[4];
            #pragma unroll
            for (int r = 0; r < 4; r++) {
                float v = acc[i][j][r] + bias[col];
                if (resf) v += resf[(rowb + r) * (long)N + col];
                if (resb) v += (float)resb[(rowb + r) * (long)N + col];
                v4[r] = v;
            }
            if (vmode == 1 && col >= 2048) {
                // vt[(bt*16+hh)][d][hw]; 4 rows = 4 consecutive hw
                const int hh = ((int)col - 2048) >> 6, d = ((int)col - 2048) & 63;
                const int r0i = (int)rowb;
                const int bt0 = r0i / HW_, hw0 = r0i - bt0 * HW_;
                bf16x4 pk;
                #pragma unroll
                for (int r = 0; r < 4; r++) pk[r] = (bf16_t)v4[r];
                *(bf16x4*)(vout + ((long)(bt0 * 16 + hh) * 64 + d) * HW_ + hw0) = pk;
            } else {
                #pragma unroll
                for (int r = 0; r < 4; r++) {
                    const long row = rowb + r;
                    long srow = row;
                    if (tperm) {
                        const int ri  = (int)row;
                        const int bb  = ri / (T_ * HW_);
                        const int rem = ri - bb * (T_ * HW_);
                        const int tt  = rem / HW_;
                        const int hh2 = rem - tt * HW_;
                        srow = ((long)bb * HW_ + hh2) * T_ + tt;
                    }
                    if (Cf) Cf[srow * (long)N + col] = v4[r];
                    if (Cb) Cb[srow * (long)N + col] = (bf16_t)v4[r];
                }
            }
        }
    }
}

// ---------------------------------------------------------------------------
// Spatial attention, MFMA flash-style (unchanged).
// ---------------------------------------------------------------------------
__global__ __launch_bounds__(256) void attn_spatial(const bf16_t* __restrict__ qkv,
                                                    const bf16_t* __restrict__ vt,
                                                    bf16_t* __restrict__ out)
{
    __shared__ bf16_t Ks[2][64 * 64];
    __shared__ bf16_t Vts[2][64 * 64];
    __shared__ bf16_t Pws[4][2][16 * 72];
    const int tid = threadIdx.x, lane = tid & 63, w = tid >> 6;
    const int qt = blockIdx.x;            // 0..4 (qt==4: 64-row tail)
    const int g  = blockIdx.y;            // 0..511
    const int h  = g & 15, bt = g >> 4;
    const long base = (long)bt * HW_;
    const int l15 = lane & 15, lhi = lane >> 4;
    const int row0 = qt * 128 + w * 16;
    const int nR = (qt == 4) ? 1 : 2;

    bf16x8 q[2][2];
    #pragma unroll
    for (int rg = 0; rg < 2; rg++) if (rg < nR) {
        #pragma unroll
        for (int kk = 0; kk < 2; kk++) {
            bf16x8 tq = *(const bf16x8*)(qkv + (base + row0 + rg * 64 + l15) * D3_
                                         + h * 64 + kk * 32 + lhi * 8);
            #pragma unroll
            for (int e = 0; e < 8; e++) tq[e] = (bf16_t)((float)tq[e] * 0.125f);
            q[rg][kk] = tq;
        }
    }

    const bf16_t* Kg = qkv + base * D3_ + 1024 + h * 64;
    const bf16_t* Vg = vt + (long)g * (64 * 576);

#define STAGEKV(kt, bq) do {                                                  \
        _Pragma("unroll")                                                     \
        for (int i_ = 0; i_ < 2; i_++) {                                      \
            const int c_ = i_ * 256 + tid;                                    \
            const int r_ = c_ >> 3, cb_ = (c_ & 7) << 4;                      \
            const int cs_ = cb_ ^ ((r_ & 7) << 4);                            \
            GLDS(Kg + (long)((kt) * 64 + r_) * D3_ + (cs_ >> 1),              \
                 (char*)Ks[bq] + c_ * 16);                                    \
            GLDS(Vg + (long)r_ * 576 + (kt) * 64 + (cs_ >> 1),               \
                 (char*)Vts[bq] + c_ * 16);                                   \
        }                                                                     \
    } while (0)

    float lp[2][4] = {};
    f32x4 o[2][4] = {};

    STAGEKV(0, 0);

    for (int kt = 0; kt < 9; kt++) {
        const int cur = kt & 1;
        __syncthreads();
        if (kt < 8) STAGEKV(kt + 1, cur ^ 1);

        f32x4 acc[2][4] = {};
        #pragma unroll
        for (int j = 0; j < 4; j++) {
            const int key = j * 16 + l15;
            #pragma unroll
            for (int kk = 0; kk < 2; kk++) {
                const int boff = key * 128 + ((kk * 64 + lhi * 16) ^ ((key & 7) << 4));
                bf16x8 kb = *(const bf16x8*)((const char*)Ks[cur] + boff);
                acc[0][j] = __builtin_amdgcn_mfma_f32_16x16x32_bf16(q[0][kk], kb, acc[0][j], 0, 0, 0);
                if (nR > 1)
                    acc[1][j] = __builtin_amdgcn_mfma_f32_16x16x32_bf16(q[1][kk], kb, acc[1][j], 0, 0, 0);
            }
        }

        #pragma unroll
        for (int rg = 0; rg < 2; rg++) if (rg < nR) {
            #pragma unroll
            for (int r = 0; r < 4; r++) {
                const float p0 = __expf(acc[rg][0][r]);
                const float p1 = __expf(acc[rg][1][r]);
                const float p2 = __expf(acc[rg][2][r]);
                const float p3 = __expf(acc[rg][3][r]);
                lp[rg][r] += (p0 + p1) + (p2 + p3);
                const int prow = (lhi * 4 + r) * 72 + l15;
                Pws[w][rg][prow]      = (bf16_t)p0;
                Pws[w][rg][prow + 16] = (bf16_t)p1;
                Pws[w][rg][prow + 32] = (bf16_t)p2;
                Pws[w][rg][prow + 48] = (bf16_t)p3;
            }
        }
        __builtin_amdgcn_sched_barrier(0);

        bf16x8 pa[2][2];
        #pragma unroll
        for (int kk = 0; kk < 2; kk++) {
            pa[0][kk] = *(const bf16x8*)&Pws[w][0][l15 * 72 + kk * 32 + lhi * 8];
            if (nR > 1)
                pa[1][kk] = *(const bf16x8*)&Pws[w][1][l15 * 72 + kk * 32 + lhi * 8];
        }
        #pragma unroll
        for (int j = 0; j < 4; j++) {
            const int vrow = j * 16 + l15;
            #pragma unroll
            for (int kk = 0; kk < 2; kk++) {
                const int boff = vrow * 128 + ((kk * 64 + lhi * 16) ^ ((vrow & 7) << 4));
                bf16x8 vb = *(const bf16x8*)((const char*)Vts[cur] + boff);
                o[0][j] = __builtin_amdgcn_mfma_f32_16x16x32_bf16(pa[0][kk], vb, o[0][j], 0, 0, 0);
                if (nR > 1)
                    o[1][j] = __builtin_amdgcn_mfma_f32_16x16x32_bf16(pa[1][kk], vb, o[1][j], 0, 0, 0);
            }
        }
        __builtin_amdgcn_sched_barrier(0);
    }
#undef STAGEKV

    #pragma unroll
    for (int rg = 0; rg < 2; rg++) if (rg < nR) {
        #pragma unroll
        for (int r = 0; r < 4; r++) {
            float l = lp[rg][r];
            #pragma unroll
            for (int off = 1; off < 16; off <<= 1) l += __shfl_xor(l, off);
            const float inv = 1.f / l;
            const long row = base + row0 + rg * 64 + lhi * 4 + r;
            #pragma unroll
            for (int j = 0; j < 4; j++)
                out[row * (long)D_ + h * 64 + j * 16 + l15] = (bf16_t)(o[rg][j][r] * inv);
        }
    }
}

// ---------------------------------------------------------------------------
// Temporal attention, MFMA; no-max softmax. Fuses the V transpose in LDS:
// phase 1 loads the block's 16 rows' V-third into tile[16][1026]; phase 2
// gathers columns to registers; phase 3 writes transposed [h][d][t] into the
// SAME LDS region (linear, 32KB <= 32.8KB); attention then reads V B-frags
// as aligned 16B LDS vectors. Replaces the vtrans_t_ip kernel.
// ---------------------------------------------------------------------------
__global__ __launch_bounds__(256) void attn_temporal(const bf16_t* __restrict__ qkv_t,
                                                     bf16_t* __restrict__ out)
{
    __shared__ bf16_t tile[16 * 1026];     // 32.8 KB; reused as vtt [h*1024+d*16+t]
    __shared__ bf16_t Plds[4][16 * 24];
    const int tid = threadIdx.x, lane = tid & 63, w = tid >> 6;
    const int l15 = lane & 15, lhi = lane >> 4;
    const int bhw = blockIdx.x;            // 0..1151
    const int b = bhw / HW_, hw = bhw % HW_;
    const long base_row = (long)bhw * T_;
    const bf16_t* qrow = qkv_t + (base_row + l15) * D3_;

    // ---- phase 1: coalesced load of V-third (16 rows x 1024) ----
    #pragma unroll
    for (int it = 0; it < 8; it++) {
        const int c = it * 256 + tid;      // 0..2047 vec8 chunks
        const int row = c >> 7, col = (c & 127) * 8;
        *(bf16x8*)&tile[row * 1026 + col] =
            *(const bf16x8*)(qkv_t + (base_row + row) * D3_ + 2048 + col);
    }
    __syncthreads();
    // ---- phase 2: gather columns to registers (all reads before writes) ----
    bf16x8 tv0[4], tv1[4];
    #pragma unroll
    for (int it = 0; it < 4; it++) {
        const int hd = it * 256 + tid;     // h*64+d, 0..1023
        #pragma unroll
        for (int t = 0; t < 8; t++) tv0[it][t] = tile[t * 1026 + hd];
        #pragma unroll
        for (int t = 0; t < 8; t++) tv1[it][t] = tile[(8 + t) * 1026 + hd];
    }
    __syncthreads();
    // ---- phase 3: write transposed vtt[hd*16 + t] ----
    #pragma unroll
    for (int it = 0; it < 4; it++) {
        const int hd = it * 256 + tid;
        *(bf16x8*)&tile[hd * 16]     = tv0[it];
        *(bf16x8*)&tile[hd * 16 + 8] = tv1[it];
    }
    __syncthreads();

    // ---- attention ----
    #pragma unroll
    for (int i = 0; i < 4; i++) {
        const int h = w * 4 + i;
        bf16x8 q0 = *(const bf16x8*)(qrow + h * 64 + lhi * 8);
        bf16x8 q1 = *(const bf16x8*)(qrow + h * 64 + 32 + lhi * 8);
        bf16x8 k0 = *(const bf16x8*)(qrow + 1024 + h * 64 + lhi * 8);
        bf16x8 k1 = *(const bf16x8*)(qrow + 1024 + h * 64 + 32 + lhi * 8);
        f32x4 acc = {};
        acc = __builtin_amdgcn_mfma_f32_16x16x32_bf16(q0, k0, acc, 0, 0, 0);
        acc = __builtin_amdgcn_mfma_f32_16x16x32_bf16(q1, k1, acc, 0, 0, 0);

        #pragma unroll
        for (int r = 0; r < 4; r++) {
            const int tq = lhi * 4 + r;
            float p = (l15 <= tq) ? __expf(acc[r] * 0.125f) : 0.f;
            float sum = p;
            #pragma unroll
            for (int off = 1; off < 16; off <<= 1) sum += __shfl_xor(sum, off);
            Plds[w][tq * 24 + l15] = (bf16_t)(p / sum);
        }
        __builtin_amdgcn_sched_barrier(0);   // pin P-write before P-read

        bf16x8 pa = {};
        if (lhi < 2) pa = *(const bf16x8*)&Plds[w][l15 * 24 + lhi * 8];

        // V from LDS vtt: [h*1024 + d*16 + t]
        #pragma unroll
        for (int j = 0; j < 4; j++) {
            bf16x8 vb = {};
            if (lhi < 2)
                vb = *(const bf16x8*)&tile[h * 1024 + (j * 16 + l15) * 16 + lhi * 8];
            f32x4 o = {};
            o = __builtin_amdgcn_mfma_f32_16x16x32_bf16(pa, vb, o, 0, 0, 0);
            #pragma unroll
            for (int r = 0; r < 4; r++) {
                const int tq = lhi * 4 + r;
                out[(((long)b * T_ + tq) * HW_ + hw) * D_ + h * 64 + j * 16 + l15] = (bf16_t)o[r];
            }
        }
        __builtin_amdgcn_sched_barrier(0);   // don't let next head's reads cross
    }
}

// ---------------------------------------------------------------------------
extern "C" void kernel_launch(void* const* d_in, const int* in_sizes, int n_in,
                              void* d_out, int out_size, void* d_ws, size_t ws_size,
                              hipStream_t stream)
{
    const float* x       = (const float*)d_in[0];
    const float* ws_qkv  = (const float*)d_in[1];
    const float* bs_qkv  = (const float*)d_in[2];
    const float* ws_proj = (const float*)d_in[3];
    const float* bs_proj = (const float*)d_in[4];
    const float* wt_qkv  = (const float*)d_in[5];
    const float* bt_qkv  = (const float*)d_in[6];
    const float* wt_proj = (const float*)d_in[7];
    const float* bt_proj = (const float*)d_in[8];
    float* out = (float*)d_out;
    (void)in_sizes; (void)n_in; (void)out_size;

    // workspace layout (bytes)
    char* ws = (char*)d_ws;
    bf16_t* qkv   = (bf16_t*)(ws);                  // 18432*3072*2 = 113,246,208
    bf16_t* x_bf  = (bf16_t*)(ws + 113246208L);     // 18432*1024*2 =  37,748,736
    bf16_t* att   = x_bf;                           // alias: att written after x_bf dead
    bf16_t* x1_bf = (bf16_t*)(ws + 150994944L);     //                 37,748,736
    bf16_t* vt    = x1_bf;                          // alias: vt dead before x1_bf written
    bf16_t* wTqs  = (bf16_t*)(ws + 188743680L);     // 3072*1024*2 =    6,291,456
    bf16_t* wTps  = (bf16_t*)(ws + 195035136L);     // 1024*1024*2 =    2,097,152
    bf16_t* wTqt  = (bf16_t*)(ws + 197132288L);     //                  6,291,456
    bf16_t* wTpt  = (bf16_t*)(ws + 203423744L);     //                  2,097,152
    if (ws_size < 205520896UL) return;              // visible failure: out stays 0

    prep<<<12288, 256, 0, stream>>>(x, x_bf, ws_qkv, wTqs, ws_proj, wTps,
                                    wt_qkv, wTqt, wt_proj, wTpt);

    // ---- spatial branch ----  (V fused into vt; x1 bf16-only)
    gemm_bt<<<24 * 144, 256, 0, stream>>>(x_bf, wTqs, bs_qkv,
                                          nullptr, nullptr,
                                          qkv, nullptr, vt, 1, 24,
                                          TOK_, D3_, D_, 0);
    attn_spatial<<<dim3(5, 512), 256, 0, stream>>>(qkv, vt, att);
    gemm_bt<<<8 * 144, 256, 0, stream>>>(att, wTps, bs_proj,
                                         x, nullptr,
                                         x1_bf, nullptr, nullptr, 0, 8,
                                         TOK_, D_, D_, 0);
    // ---- temporal branch ----  (qkv rows (b,hw,t); V transposed in-LDS
    //      inside attn_temporal — no separate transpose kernel)
    gemm_bt<<<24 * 144, 256, 0, stream>>>(x1_bf, wTqt, bt_qkv,
                                          nullptr, nullptr,
                                          qkv, nullptr, nullptr, 0, 24,
                                          TOK_, D3_, D_, 1);
    attn_temporal<<<1152, 256, 0, stream>>>(qkv, att);
    gemm_bt<<<8 * 144, 256, 0, stream>>>(att, wTpt, bt_proj,
                                         nullptr, x1_bf,
                                         nullptr, out, nullptr, 0, 8,
                                         TOK_, D_, D_, 0);
}